// Round 8
// baseline (432.581 us; speedup 1.0000x reference)
//
#include <hip/hip_runtime.h>
#include <math.h>

#define DEPTH 18
#define NINT ((1 << (DEPTH - 1)) - 1)      // internal nodes = 131071
#define LEAF_OFF ((1 << (DEPTH - 2)) - 1)  // first level-16 node = 65535
#define NVOCAB 50000
#define SAW 520                             // sA row stride: [x|hs|h1|h2] + pad

typedef unsigned short bf16raw;
typedef __bf16 bf16x8 __attribute__((ext_vector_type(8)));
typedef float f32x4 __attribute__((ext_vector_type(4)));
typedef short short8 __attribute__((ext_vector_type(8)));

__device__ __forceinline__ float sigm(float x) { return 1.0f / (1.0f + __expf(-x)); }
// NaN-safe fast tanh (saturates correctly at +-inf).
__device__ __forceinline__ float fast_tanh(float x) {
    float t = __expf(2.0f * x);
    return 1.0f - 2.0f / (t + 1.0f);
}

__device__ __forceinline__ float bf2f(bf16raw u) {
    union { unsigned int i; float f; } v;
    v.i = ((unsigned int)u) << 16;
    return v.f;
}
__device__ __forceinline__ bf16raw f2bf(float f) {
    union { float f; unsigned int i; } v;
    v.f = f;
    unsigned int r = v.i + 0x7FFFu + ((v.i >> 16) & 1u);  // RNE
    return (bf16raw)(r >> 16);
}

#define SB() __builtin_amdgcn_sched_barrier(0)

// ---------------------------------------------------------------------------
__global__ __launch_bounds__(256) void k_prep_embeds(const float* __restrict__ src,
                                                     bf16raw* __restrict__ dst, int n4)
{
    int i = blockIdx.x * blockDim.x + threadIdx.x;
    if (i < n4) {
        float4 v = ((const float4*)src)[i];
        ushort4 o;
        o.x = f2bf(v.x); o.y = f2bf(v.y); o.z = f2bf(v.z); o.w = f2bf(v.w);
        ((ushort4*)dst)[i] = o;
    }
}

// ---------------------------------------------------------------------------
// Bfrag: fragment-linear, dedup'd B.  Gates: 0=i, 1=u, 2=o, 3=f; each gate
// [Wx|Wh], K=256 (8 ktiles).  Physical:
//   Bfrag[(((gate*8+coltile)*8+ktile)*64 + lane)*8 + e]
//   coltile=col>>4, lane=((k>>3)&3)*16+(col&15), ktile=k>>5, e=k&7.
// Wave B-fragment load = 64 consecutive 16B chunks = one coalesced 1KB txn.
// ---------------------------------------------------------------------------
__global__ __launch_bounds__(128) void k_prep_bcat(
    const float* __restrict__ Wix, const float* __restrict__ bix,
    const float* __restrict__ Wih, const float* __restrict__ bih,
    const float* __restrict__ Wfx, const float* __restrict__ bfx,
    const float* __restrict__ Wfh, const float* __restrict__ bfh,
    const float* __restrict__ Wox, const float* __restrict__ box_,
    const float* __restrict__ Woh, const float* __restrict__ boh,
    const float* __restrict__ Wux, const float* __restrict__ bux,
    const float* __restrict__ Wuh, const float* __restrict__ buh,
    bf16raw* __restrict__ Bfrag, float* __restrict__ bias_cat)
{
    const int j = blockIdx.x;        // 0..511 = gate*128 + col
    const int gate = j >> 7, jj = j & 127;
    const float *Wx, *Wh, *bx, *bh;
    switch (gate) {
        case 0: Wx = Wix; Wh = Wih; bx = bix;  bh = bih; break;
        case 1: Wx = Wux; Wh = Wuh; bx = bux;  bh = buh; break;
        case 2: Wx = Wox; Wh = Woh; bx = box_; bh = boh; break;
        default: Wx = Wfx; Wh = Wfh; bx = bfx; bh = bfh; break;
    }
    const int coltile = (j >> 4) & 7, lr = j & 15;
    for (int k = threadIdx.x; k < 256; k += blockDim.x) {
        float v = (k < 128) ? Wx[jj * 128 + k] : Wh[jj * 128 + (k - 128)];
        const int idx = (((gate * 8 + coltile) * 8 + (k >> 5)) * 64
                         + ((k >> 3) & 3) * 16 + lr) * 8 + (k & 7);
        Bfrag[idx] = f2bf(v);
    }
    if (threadIdx.x == 0) bias_cat[j] = bx[jj] + bh[jj];
}

// ---------------------------------------------------------------------------
// k_leafpre burst helpers (unchanged from round 7).
// ---------------------------------------------------------------------------
template<int CB>
__device__ __forceinline__ void lp_burst(const bf16raw* __restrict__ bfbase, int wcol,
                                         bf16x8 (&bb)[16])
{
#pragma unroll
    for (int kt = 0; kt < 4; ++kt)
#pragma unroll
        for (int j = 0; j < 4; ++j)
            bb[kt * 4 + j] = *(const bf16x8*)(bfbase +
                    (long)(((CB * 8 + (wcol >> 4) + j) * 8 + kt) * 512));
}

__device__ __forceinline__ void lp_mfma_all(const bf16raw* __restrict__ sA, int wrow,
                                            int lrow, int lquad,
                                            bf16x8 (&bb)[16], f32x4 (&acc)[4][4])
{
#pragma unroll
    for (int kt = 0; kt < 4; ++kt) {
        bf16x8 af[4];
#pragma unroll
        for (int i = 0; i < 4; ++i)
            af[i] = *(const bf16x8*)&sA[(wrow + i * 16 + lrow) * 136 + kt * 32 + lquad * 8];
#pragma unroll
        for (int i = 0; i < 4; ++i)
#pragma unroll
            for (int j = 0; j < 4; ++j)
                acc[i][j] = __builtin_amdgcn_mfma_f32_16x16x32_bf16(af[i], bb[kt * 4 + j], acc[i][j], 0, 0, 0);
    }
}

template<int CB>
__device__ __forceinline__ void lp_rungemm(const bf16raw* __restrict__ sA,
                                           const bf16raw* __restrict__ bfbase,
                                           int wrow, int wcol, int lrow, int lquad,
                                           f32x4 (&acc)[4][4])
{
#pragma unroll
    for (int i = 0; i < 4; i++)
#pragma unroll
        for (int j = 0; j < 4; j++) acc[i][j] = (f32x4){0.f, 0.f, 0.f, 0.f};
    bf16x8 bb[16];
    lp_burst<CB>(bfbase, wcol, bb);
    SB();
    lp_mfma_all(sA, wrow, lrow, lquad, bb, acc);
}

// ---------------------------------------------------------------------------
// k_level half-burst helpers.  Wave w: coltiles w*2, w*2+1.
// PASS: 0=i, 1=u, 2=f1, 3=f2, 4=o.  Bfrag gate index per burst: i=0,u=1,f=3,o=2.
// ---------------------------------------------------------------------------
template<int G, int H>
__device__ __forceinline__ void load8(const bf16raw* __restrict__ bfbase, int w,
                                      bf16x8 (&bb)[8])
{
#pragma unroll
    for (int kt2 = 0; kt2 < 4; ++kt2)
#pragma unroll
        for (int jj = 0; jj < 2; ++jj)
            bb[kt2 * 2 + jj] = *(const bf16x8*)(bfbase +
                    (long)(((G * 8 + w * 2 + jj) * 8 + H * 4 + kt2) * 512));
}

// A-ktile map: i/u/o over [x|hs] (0..7); f1 H1 -> h1 (8..11); f2 H1 -> h2 (12..15).
template<int PASS, int H>
__device__ __forceinline__ void mfma8(const bf16raw* __restrict__ sA, int lrow, int lquad,
                                      bf16x8 (&bb)[8], f32x4 (&acc)[2][2])
{
    constexpr int base = (PASS == 2) ? (H ? 8 : 0)
                       : (PASS == 3) ? (H ? 12 : 0)
                       : H * 4;
#pragma unroll
    for (int kt2 = 0; kt2 < 4; ++kt2) {
        bf16x8 af[2];
#pragma unroll
        for (int i = 0; i < 2; ++i)
            af[i] = *(const bf16x8*)&sA[(i * 16 + lrow) * SAW + (base + kt2) * 32 + lquad * 8];
#pragma unroll
        for (int jj = 0; jj < 2; ++jj)
#pragma unroll
            for (int i = 0; i < 2; ++i)
                acc[i][jj] = __builtin_amdgcn_mfma_f32_16x16x32_bf16(af[i], bb[kt2 * 2 + jj], acc[i][jj], 0, 0, 0);
    }
}

// ---------------------------------------------------------------------------
// k_leafpre: per-vocab leaf tables (h, c, logits, lse).  Unchanged structure;
// logits loop vectorized (short8 LDS reads).
// ---------------------------------------------------------------------------
__global__ __launch_bounds__(256, 2) void k_leafpre(
    const bf16raw* __restrict__ embeds_bf,
    const bf16raw* __restrict__ Bfrag, const float* __restrict__ bias_cat,
    const float* __restrict__ Wout, const float* __restrict__ bout,
    bf16raw* __restrict__ hc_leaf, float* __restrict__ lossv6, int vbase, int nv)
{
    vbase += blockIdx.x * 128;
    nv -= vbase;
    if (nv > 128) nv = 128;
    if (nv <= 0) return;

    __shared__ __align__(16) bf16raw sA[128 * 136];
    __shared__ __align__(16) bf16raw sT[128 * 136];
    __shared__ float sWout[5 * 128];

    const int t = threadIdx.x;
    for (int i = t; i < 640; i += 256) sWout[i] = Wout[i];

    {
        const int row = t >> 1;
        const int half = (t & 1) * 64;
        const int arow = (row < nv) ? row : 0;
        const bf16raw* ax = embeds_bf + (long)(vbase + arow) * 128;
#pragma unroll
        for (int s = 0; s < 8; ++s)
            *(short8*)&sA[row * 136 + half + s * 8] = *(const short8*)(ax + half + s * 8);
    }

    const int lane = t & 63;
    const int w = t >> 6;
    const int wrow = (w >> 1) * 64;
    const int wcol = (w & 1) * 64;
    const int lrow = lane & 15;
    const int lquad = lane >> 4;

    __syncthreads();

    const bf16raw* bfbase = Bfrag + (long)lane * 8;

    float tval[4][4][4];
    f32x4 acc[4][4];

    // ---- i gate ----
    lp_rungemm<0>(sA, bfbase, wrow, wcol, lrow, lquad, acc);
#pragma unroll
    for (int i = 0; i < 4; i++)
#pragma unroll
        for (int jj = 0; jj < 4; jj++) {
            const float b = bias_cat[wcol + jj * 16 + lrow];
#pragma unroll
            for (int r = 0; r < 4; r++) tval[i][jj][r] = sigm(acc[i][jj][r] + b);
        }
    // ---- u gate: tval = c = i*u ----
    lp_rungemm<1>(sA, bfbase, wrow, wcol, lrow, lquad, acc);
#pragma unroll
    for (int i = 0; i < 4; i++)
#pragma unroll
        for (int jj = 0; jj < 4; jj++) {
            const float b = bias_cat[128 + wcol + jj * 16 + lrow];
#pragma unroll
            for (int r = 0; r < 4; r++) tval[i][jj][r] *= fast_tanh(acc[i][jj][r] + b);
        }
    // write c tile, keep tanh(c) in regs
#pragma unroll
    for (int i = 0; i < 4; i++)
#pragma unroll
        for (int jj = 0; jj < 4; jj++)
#pragma unroll
            for (int r = 0; r < 4; r++) {
                const int m = wrow + i * 16 + lquad * 4 + r;
                const int j = wcol + jj * 16 + lrow;
                sT[m * 136 + j] = f2bf(tval[i][jj][r]);
            }
#pragma unroll
    for (int i = 0; i < 4; i++)
#pragma unroll
        for (int jj = 0; jj < 4; jj++)
#pragma unroll
            for (int r = 0; r < 4; r++) tval[i][jj][r] = fast_tanh(tval[i][jj][r]);
    __syncthreads();
#pragma unroll
    for (int s = 0; s < 8; ++s) {
        int ci = t + 256 * s;
        int row = ci >> 4, c8 = (ci & 15) * 8;
        if (row < nv)
            *(short8*)(hc_leaf + (long)(vbase + row) * 256 + 128 + c8) = *(const short8*)&sT[row * 136 + c8];
    }
    // ---- o gate: h = sigm(o)*tanh(c) ----
    lp_rungemm<2>(sA, bfbase, wrow, wcol, lrow, lquad, acc);
    __syncthreads();
#pragma unroll
    for (int i = 0; i < 4; i++)
#pragma unroll
        for (int jj = 0; jj < 4; jj++) {
            const float b = bias_cat[256 + wcol + jj * 16 + lrow];
#pragma unroll
            for (int r = 0; r < 4; r++) {
                const int m = wrow + i * 16 + lquad * 4 + r;
                const int j = wcol + jj * 16 + lrow;
                sT[m * 136 + j] = f2bf(sigm(acc[i][jj][r] + b) * tval[i][jj][r]);
            }
        }
    __syncthreads();
#pragma unroll
    for (int s = 0; s < 8; ++s) {
        int ci = t + 256 * s;
        int row = ci >> 4, c8 = (ci & 15) * 8;
        if (row < nv)
            *(short8*)(hc_leaf + (long)(vbase + row) * 256 + c8) = *(const short8*)&sT[row * 136 + c8];
    }
    // logits + lse per vocab row (vectorized)
    {
        const int row = t >> 1, half = t & 1;
        float p[5] = {0.f, 0.f, 0.f, 0.f, 0.f};
        const bf16raw* rp = &sT[row * 136 + half * 64];
#pragma unroll
        for (int s = 0; s < 8; ++s) {
            short8 v = *(const short8*)(rp + s * 8);
#pragma unroll
            for (int e = 0; e < 8; ++e) {
                float hv = bf2f((bf16raw)(unsigned short)v[e]);
#pragma unroll
                for (int l = 0; l < 5; l++) p[l] += hv * sWout[l * 128 + half * 64 + s * 8 + e];
            }
        }
#pragma unroll
        for (int l = 0; l < 5; l++) p[l] += __shfl_down(p[l], 1);
        if (half == 0 && row < nv) {
            float lg[5], mx = -1e30f;
#pragma unroll
            for (int l = 0; l < 5; l++) {
                lg[l] = p[l] + bout[l];
                mx = fmaxf(mx, lg[l]);
            }
            float se = 0.f;
#pragma unroll
            for (int l = 0; l < 5; l++) se += __expf(lg[l] - mx);
            float lse = __logf(se) + mx;
            float* dst = lossv6 + (long)(vbase + row) * 6;
#pragma unroll
            for (int l = 0; l < 5; l++) dst[l] = lg[l];
            dst[5] = lse;
        }
    }
}

// ---------------------------------------------------------------------------
// level_body: one level chunk of 32 nodes (m0..m0+31).  Fold-after-pass
// design: each gate's accumulator is folded into the running cell state
// immediately, so only acc[2][2] (16) + stash (~32) are live -> ~150 unified
// regs -> 3 blocks/CU (vs round-7's acc[5][2][2]=80 AGPR -> 2 blocks).
// Loss/logits epilogue removed (handled by k_loss over h_all at the end).
// ---------------------------------------------------------------------------
__device__ __forceinline__ void level_body(
    const bf16raw* __restrict__ embeds_bf, const int* __restrict__ words,
    bf16raw* __restrict__ h_all, bf16raw* __restrict__ c_all,
    const bf16raw* __restrict__ hc_leaf,
    const bf16raw* __restrict__ Bfrag, const float* __restrict__ bias_cat,
    bf16raw* sA, bf16raw* sCT,
    int off, int m0, int nm, int leafkids)
{
    const int t = threadIdx.x;

    // ---- stage A tile [x|hs|h1|h2]: 8 threads/row ----
    {
        const int row = t >> 3;
        const int co = (t & 7) * 8;
        int mm = m0 + row; if (mm >= nm) mm = nm - 1;
        const long g = (long)off + mm;
        const bf16raw* px = embeds_bf + (long)words[g] * 128;
        const bf16raw *p1, *p2;
        if (leafkids) {
            p1 = hc_leaf + (long)words[2 * g + 1] * 256;
            p2 = hc_leaf + (long)words[2 * g + 2] * 256;
        } else {
            p1 = h_all + (2 * g + 1) * 128;
            p2 = h_all + (2 * g + 2) * 128;
        }
        short8 vx0 = *(const short8*)(px + co);
        short8 vx1 = *(const short8*)(px + 64 + co);
        short8 h10 = *(const short8*)(p1 + co);
        short8 h11 = *(const short8*)(p1 + 64 + co);
        short8 h20 = *(const short8*)(p2 + co);
        short8 h21 = *(const short8*)(p2 + 64 + co);
        short8 hs0, hs1;
#pragma unroll
        for (int e = 0; e < 8; ++e) {
            hs0[e] = (short)f2bf(bf2f((bf16raw)(unsigned short)h10[e]) +
                                 bf2f((bf16raw)(unsigned short)h20[e]));
            hs1[e] = (short)f2bf(bf2f((bf16raw)(unsigned short)h11[e]) +
                                 bf2f((bf16raw)(unsigned short)h21[e]));
        }
        *(short8*)&sA[row * SAW + co]        = vx0;
        *(short8*)&sA[row * SAW + 64 + co]   = vx1;
        *(short8*)&sA[row * SAW + 128 + co]  = hs0;
        *(short8*)&sA[row * SAW + 192 + co]  = hs1;
        *(short8*)&sA[row * SAW + 256 + co]  = h10;
        *(short8*)&sA[row * SAW + 320 + co]  = h11;
        *(short8*)&sA[row * SAW + 384 + co]  = h20;
        *(short8*)&sA[row * SAW + 448 + co]  = h21;
    }
    // ---- stage children c: slot = 2*mlocal + childIdx ----
    {
        const int slot = t >> 2;
        const int cc8 = (t & 3) * 8;
        int mm = m0 + (slot >> 1); if (mm >= nm) mm = nm - 1;
        const long g = (long)off + mm;
        const long cg = 2 * g + 1 + (slot & 1);
        const bf16raw* pc = leafkids ? (hc_leaf + (long)words[cg] * 256 + 128)
                                     : (c_all + cg * 128);
#pragma unroll
        for (int s = 0; s < 4; ++s)
            *(short8*)&sCT[slot * 136 + s * 32 + cc8] = *(const short8*)(pc + s * 32 + cc8);
    }

    const int lane = t & 63;
    const int w = t >> 6;
    const int lrow = lane & 15;
    const int lquad = lane >> 4;

    // bias preload (gate order 0=i,1=u,2=o,3=f)
    float bias[4][2];
#pragma unroll
    for (int g = 0; g < 4; ++g)
#pragma unroll
        for (int jj = 0; jj < 2; ++jj)
            bias[g][jj] = bias_cat[g * 128 + w * 32 + jj * 16 + lrow];

    __syncthreads();   // A tile + children staged

    const bf16raw* bfbase = Bfrag + (long)lane * 8;

    f32x4 acc[2][2];
    float si[2][2][4];   // sigm(i) stash
    float cc[2][2][4];   // running c
    float hh[2][2][4];   // final h
    bf16x8 bbA[8], bbB[8];

#define ZACC() { _Pragma("unroll") for (int i_ = 0; i_ < 2; ++i_) \
                 _Pragma("unroll") for (int j_ = 0; j_ < 2; ++j_) \
                     acc[i_][j_] = (f32x4){0.f, 0.f, 0.f, 0.f}; }

    load8<0, 0>(bfbase, w, bbA);
    load8<0, 1>(bfbase, w, bbB);
    SB();
    ZACC();
    mfma8<0, 0>(sA, lrow, lquad, bbA, acc); SB();
    load8<1, 0>(bfbase, w, bbA); SB();
    mfma8<0, 1>(sA, lrow, lquad, bbB, acc); SB();
    load8<1, 1>(bfbase, w, bbB); SB();
    // fold i
#pragma unroll
    for (int i = 0; i < 2; ++i)
#pragma unroll
        for (int jj = 0; jj < 2; ++jj)
#pragma unroll
            for (int r = 0; r < 4; ++r)
                si[i][jj][r] = sigm(acc[i][jj][r] + bias[0][jj]);
    ZACC();
    mfma8<1, 0>(sA, lrow, lquad, bbA, acc); SB();
    load8<3, 0>(bfbase, w, bbA); SB();
    mfma8<1, 1>(sA, lrow, lquad, bbB, acc); SB();
    load8<3, 1>(bfbase, w, bbB); SB();
    // fold u: cc = sigm(i) * tanh(u)
#pragma unroll
    for (int i = 0; i < 2; ++i)
#pragma unroll
        for (int jj = 0; jj < 2; ++jj)
#pragma unroll
            for (int r = 0; r < 4; ++r)
                cc[i][jj][r] = si[i][jj][r] * fast_tanh(acc[i][jj][r] + bias[1][jj]);
    ZACC();
    mfma8<2, 0>(sA, lrow, lquad, bbA, acc);
    mfma8<2, 1>(sA, lrow, lquad, bbB, acc);
    SB();
    // fold f1: cc += sigm(f1) * c1
#pragma unroll
    for (int i = 0; i < 2; ++i)
#pragma unroll
        for (int jj = 0; jj < 2; ++jj) {
            const int j = w * 32 + jj * 16 + lrow;
#pragma unroll
            for (int r = 0; r < 4; ++r) {
                const int m = i * 16 + lquad * 4 + r;
                cc[i][jj][r] += sigm(acc[i][jj][r] + bias[3][jj]) * bf2f(sCT[(2 * m) * 136 + j]);
            }
        }
    ZACC();
    mfma8<3, 0>(sA, lrow, lquad, bbA, acc);
    mfma8<3, 1>(sA, lrow, lquad, bbB, acc);
    SB();
    load8<2, 0>(bfbase, w, bbA);
    load8<2, 1>(bfbase, w, bbB);
    SB();
    // fold f2: cc += sigm(f2) * c2   (overlaps o-burst latency)
#pragma unroll
    for (int i = 0; i < 2; ++i)
#pragma unroll
        for (int jj = 0; jj < 2; ++jj) {
            const int j = w * 32 + jj * 16 + lrow;
#pragma unroll
            for (int r = 0; r < 4; ++r) {
                const int m = i * 16 + lquad * 4 + r;
                cc[i][jj][r] += sigm(acc[i][jj][r] + bias[3][jj]) * bf2f(sCT[(2 * m + 1) * 136 + j]);
            }
        }
    ZACC();
    mfma8<4, 0>(sA, lrow, lquad, bbA, acc);
    mfma8<4, 1>(sA, lrow, lquad, bbB, acc);
    SB();
    // fold o: hh = sigm(o) * tanh(cc)
#pragma unroll
    for (int i = 0; i < 2; ++i)
#pragma unroll
        for (int jj = 0; jj < 2; ++jj)
#pragma unroll
            for (int r = 0; r < 4; ++r)
                hh[i][jj][r] = sigm(acc[i][jj][r] + bias[2][jj]) * fast_tanh(cc[i][jj][r]);
#undef ZACC

    __syncthreads();   // all sCT child reads done

    // ---- write c (rows 0..31) / h (rows 32..63) tiles into sCT ----
#pragma unroll
    for (int i = 0; i < 2; ++i)
#pragma unroll
        for (int jj = 0; jj < 2; ++jj) {
            const int j = w * 32 + jj * 16 + lrow;
#pragma unroll
            for (int r = 0; r < 4; ++r) {
                const int m = i * 16 + lquad * 4 + r;
                sCT[m * 136 + j] = f2bf(cc[i][jj][r]);
                sCT[(32 + m) * 136 + j] = f2bf(hh[i][jj][r]);
            }
        }
    __syncthreads();

    // ---- coalesced flush ----
#pragma unroll
    for (int q = 0; q < 4; ++q) {
        int ci = t + 256 * q;
        int row = ci >> 4;
        int c8 = (ci & 15) * 8;
        int m = row & 31;
        if (m0 + m < nm) {
            bf16raw* dst = (row < 32) ? c_all : h_all;
            *(short8*)(dst + ((long)off + m0 + m) * 128 + c8) = *(const short8*)&sCT[row * 136 + c8];
        }
    }
}

// ---------------------------------------------------------------------------
__global__ __launch_bounds__(256, 3) void k_level32(
    const bf16raw* __restrict__ embeds_bf, const int* __restrict__ words,
    bf16raw* __restrict__ h_all, bf16raw* __restrict__ c_all,
    const bf16raw* __restrict__ hc_leaf,
    const bf16raw* __restrict__ Bfrag, const float* __restrict__ bias_cat,
    int off, int nm, int leafkids)
{
    __shared__ __align__(16) bf16raw sA[32 * SAW];
    __shared__ __align__(16) bf16raw sCT[64 * 136];
    level_body(embeds_bf, words, h_all, c_all, hc_leaf, Bfrag, bias_cat,
               sA, sCT, off, blockIdx.x * 32, nm, leafkids);
}

// Levels 5..0 fused into one block (63 nodes total; intra-block barrier is a
// legal level barrier — global writes drain at __syncthreads).
__global__ __launch_bounds__(256, 3) void k_level_tail(
    const bf16raw* __restrict__ embeds_bf, const int* __restrict__ words,
    bf16raw* __restrict__ h_all, bf16raw* __restrict__ c_all,
    const bf16raw* __restrict__ hc_leaf,
    const bf16raw* __restrict__ Bfrag, const float* __restrict__ bias_cat)
{
    __shared__ __align__(16) bf16raw sA[32 * SAW];
    __shared__ __align__(16) bf16raw sCT[64 * 136];
    for (int l = 5; l >= 0; --l) {
        __syncthreads();
        const int n = 1 << l;
        level_body(embeds_bf, words, h_all, c_all, hc_leaf, Bfrag, bias_cat,
                   sA, sCT, n - 1, 0, n, 0);
    }
}

// ---------------------------------------------------------------------------
// k_loss: one pass over all internal nodes.  2 threads/node; logits via
// Wout GEMV from h_all; level-16 nodes add their leaf children's terms from
// lossv6; root writes out[0..4]; per-block partial into partials.
// ---------------------------------------------------------------------------
__global__ __launch_bounds__(256) void k_loss(
    const bf16raw* __restrict__ h_all, const int* __restrict__ words,
    const int* __restrict__ labels, const float* __restrict__ lossv6,
    const float* __restrict__ Wout, const float* __restrict__ bout,
    float* __restrict__ partials, float* __restrict__ out)
{
    __shared__ float sWout[640];
    __shared__ float red[128];
    const int t = threadIdx.x;
    for (int i = t; i < 640; i += 256) sWout[i] = Wout[i];

    const int row = t >> 1, half = t & 1;
    const long g = (long)blockIdx.x * 128 + row;
    const bool valid = g < NINT;
    const long gg = valid ? g : 0;
    __syncthreads();

    float p[5] = {0.f, 0.f, 0.f, 0.f, 0.f};
    const bf16raw* hp = h_all + gg * 128 + half * 64;
#pragma unroll
    for (int s = 0; s < 8; ++s) {
        short8 v = *(const short8*)(hp + s * 8);
#pragma unroll
        for (int e = 0; e < 8; ++e) {
            float hv = bf2f((bf16raw)(unsigned short)v[e]);
#pragma unroll
            for (int l = 0; l < 5; l++) p[l] += hv * sWout[l * 128 + half * 64 + s * 8 + e];
        }
    }
#pragma unroll
    for (int l = 0; l < 5; l++) p[l] += __shfl_down(p[l], 1);

    float lossNode = 0.f;
    if (half == 0 && valid) {
        float lg[5], mx = -1e30f;
#pragma unroll
        for (int l = 0; l < 5; l++) {
            lg[l] = p[l] + bout[l];
            mx = fmaxf(mx, lg[l]);
        }
        float se = 0.f;
#pragma unroll
        for (int l = 0; l < 5; l++) se += __expf(lg[l] - mx);
        float lse = __logf(se) + mx;
        lossNode = lse - lg[labels[gg]];
        if (gg >= LEAF_OFF) {   // level-16 node: add leaf children terms
            const float* lv1 = lossv6 + (long)words[2 * gg + 1] * 6;
            const float* lv2 = lossv6 + (long)words[2 * gg + 2] * 6;
            lossNode += (lv1[5] - lv1[labels[2 * gg + 1]])
                      + (lv2[5] - lv2[labels[2 * gg + 2]]);
        }
        if (gg == 0) {
#pragma unroll
            for (int l = 0; l < 5; l++) out[l] = lg[l] - lse;
        }
    }
    if (half == 0) red[row] = lossNode;
    __syncthreads();
    if (t < 64) {
        float s = red[t] + red[t + 64];
#pragma unroll
        for (int d = 32; d > 0; d >>= 1) s += __shfl_down(s, d);
        if (t == 0) atomicAdd(&partials[blockIdx.x & 1023], s);
    }
}

__global__ __launch_bounds__(256) void k3_reduce(const float* __restrict__ partials,
                                                 float* __restrict__ out)
{
    const int t = threadIdx.x;
    float s = 0.f;
    for (int i = t; i < 1024; i += 256) s += partials[i];
#pragma unroll
    for (int d = 32; d > 0; d >>= 1) s += __shfl_down(s, d);
    __shared__ float red[4];
    if ((t & 63) == 0) red[t >> 6] = s;
    __syncthreads();
    if (t == 0) out[5] = red[0] + red[1] + red[2] + red[3];
}

// ---------------------------------------------------------------------------
extern "C" void kernel_launch(void* const* d_in, const int* in_sizes, int n_in,
                              void* d_out, int out_size, void* d_ws, size_t ws_size,
                              hipStream_t stream)
{
    const float* embeds = (const float*)d_in[0];
    const int* words = (const int*)d_in[1];
    const int* labels = (const int*)d_in[2];
    const float* Wix = (const float*)d_in[5],  *bix  = (const float*)d_in[6];
    const float* Wih = (const float*)d_in[7],  *bih  = (const float*)d_in[8];
    const float* Wfx = (const float*)d_in[9],  *bfx  = (const float*)d_in[10];
    const float* Wfh = (const float*)d_in[11], *bfh  = (const float*)d_in[12];
    const float* Wox = (const float*)d_in[13], *box_ = (const float*)d_in[14];
    const float* Woh = (const float*)d_in[15], *boh  = (const float*)d_in[16];
    const float* Wux = (const float*)d_in[17], *bux  = (const float*)d_in[18];
    const float* Wuh = (const float*)d_in[19], *buh  = (const float*)d_in[20];
    const float* Wout = (const float*)d_in[21], *bout = (const float*)d_in[22];
    float* out = (float*)d_out;

    char* ws = (char*)d_ws;
    const size_t treeElems = (size_t)NINT * 128;
    bf16raw* h_all = (bf16raw*)ws;
    bf16raw* c_all = h_all + treeElems;
    bf16raw* embeds_bf = c_all + treeElems;
    bf16raw* Bfrag = embeds_bf + (size_t)NVOCAB * 128;
    bf16raw* hc_leaf = Bfrag + 4 * 8 * 8 * 512;          // 256KB dedup B
    float* lossv6 = (float*)(hc_leaf + (size_t)NVOCAB * 256);
    float* bias_cat = lossv6 + (size_t)NVOCAB * 6;
    float* partials = bias_cat + 512;

    k_prep_embeds<<<(NVOCAB * 128 / 4 + 255) / 256, 256, 0, stream>>>(
        embeds, embeds_bf, NVOCAB * 128 / 4);
    k_prep_bcat<<<512, 128, 0, stream>>>(Wix, bix, Wih, bih, Wfx, bfx, Wfh, bfh,
                                         Wox, box_, Woh, boh, Wux, bux, Wuh, buh,
                                         Bfrag, bias_cat);
    hipMemsetAsync(partials, 0, 1024 * sizeof(float), stream);

    k_leafpre<<<(NVOCAB + 127) / 128, 256, 0, stream>>>(
        embeds_bf, Bfrag, bias_cat, Wout, bout, hc_leaf, lossv6, 0, NVOCAB);

    for (int l = DEPTH - 2; l >= 6; --l) {
        const int n = 1 << l;
        k_level32<<<dim3((n + 31) / 32), 256, 0, stream>>>(
            embeds_bf, words, h_all, c_all, hc_leaf, Bfrag, bias_cat,
            n - 1, n, (l == DEPTH - 2) ? 1 : 0);
    }
    k_level_tail<<<1, 256, 0, stream>>>(embeds_bf, words, h_all, c_all, hc_leaf,
                                        Bfrag, bias_cat);

    k_loss<<<(NINT + 127) / 128, 256, 0, stream>>>(
        h_all, words, labels, lossv6, Wout, bout, partials, out);
    k3_reduce<<<1, 256, 0, stream>>>(partials, out);
}

// Round 9
// 377.979 us; speedup vs baseline: 1.1445x; 1.1445x over previous
//
#include <hip/hip_runtime.h>
#include <math.h>

#define DEPTH 18
#define NINT ((1 << (DEPTH - 1)) - 1)      // internal nodes = 131071
#define LEAF_OFF ((1 << (DEPTH - 2)) - 1)  // first level-16 node = 65535
#define NVOCAB 50000
#define SAW 520                             // sA row stride: [x|hs|h1|h2] + pad

typedef unsigned short bf16raw;
typedef __bf16 bf16x8 __attribute__((ext_vector_type(8)));
typedef float f32x4 __attribute__((ext_vector_type(4)));
typedef short short8 __attribute__((ext_vector_type(8)));

__device__ __forceinline__ float sigm(float x) { return 1.0f / (1.0f + __expf(-x)); }
// NaN-safe fast tanh (saturates correctly at +-inf).
__device__ __forceinline__ float fast_tanh(float x) {
    float t = __expf(2.0f * x);
    return 1.0f - 2.0f / (t + 1.0f);
}

__device__ __forceinline__ float bf2f(bf16raw u) {
    union { unsigned int i; float f; } v;
    v.i = ((unsigned int)u) << 16;
    return v.f;
}
__device__ __forceinline__ bf16raw f2bf(float f) {
    union { float f; unsigned int i; } v;
    v.f = f;
    unsigned int r = v.i + 0x7FFFu + ((v.i >> 16) & 1u);  // RNE
    return (bf16raw)(r >> 16);
}

#define SB() __builtin_amdgcn_sched_barrier(0)

// ---------------------------------------------------------------------------
__global__ __launch_bounds__(256) void k_prep_embeds(const float* __restrict__ src,
                                                     bf16raw* __restrict__ dst, int n4)
{
    int i = blockIdx.x * blockDim.x + threadIdx.x;
    if (i < n4) {
        float4 v = ((const float4*)src)[i];
        ushort4 o;
        o.x = f2bf(v.x); o.y = f2bf(v.y); o.z = f2bf(v.z); o.w = f2bf(v.w);
        ((ushort4*)dst)[i] = o;
    }
}

// ---------------------------------------------------------------------------
// Bfrag: fragment-linear, dedup'd B.  Gates: 0=i, 1=u, 2=o, 3=f; each gate
// [Wx|Wh], K=256 (8 ktiles).  Physical:
//   Bfrag[(((gate*8+coltile)*8+ktile)*64 + lane)*8 + e]
//   coltile=col>>4, lane=((k>>3)&3)*16+(col&15), ktile=k>>5, e=k&7.
// Wave B-fragment load = 64 consecutive 16B chunks = one coalesced 1KB txn.
// ---------------------------------------------------------------------------
__global__ __launch_bounds__(128) void k_prep_bcat(
    const float* __restrict__ Wix, const float* __restrict__ bix,
    const float* __restrict__ Wih, const float* __restrict__ bih,
    const float* __restrict__ Wfx, const float* __restrict__ bfx,
    const float* __restrict__ Wfh, const float* __restrict__ bfh,
    const float* __restrict__ Wox, const float* __restrict__ box_,
    const float* __restrict__ Woh, const float* __restrict__ boh,
    const float* __restrict__ Wux, const float* __restrict__ bux,
    const float* __restrict__ Wuh, const float* __restrict__ buh,
    bf16raw* __restrict__ Bfrag, float* __restrict__ bias_cat)
{
    const int j = blockIdx.x;        // 0..511 = gate*128 + col
    const int gate = j >> 7, jj = j & 127;
    const float *Wx, *Wh, *bx, *bh;
    switch (gate) {
        case 0: Wx = Wix; Wh = Wih; bx = bix;  bh = bih; break;
        case 1: Wx = Wux; Wh = Wuh; bx = bux;  bh = buh; break;
        case 2: Wx = Wox; Wh = Woh; bx = box_; bh = boh; break;
        default: Wx = Wfx; Wh = Wfh; bx = bfx; bh = bfh; break;
    }
    const int coltile = (j >> 4) & 7, lr = j & 15;
    for (int k = threadIdx.x; k < 256; k += blockDim.x) {
        float v = (k < 128) ? Wx[jj * 128 + k] : Wh[jj * 128 + (k - 128)];
        const int idx = (((gate * 8 + coltile) * 8 + (k >> 5)) * 64
                         + ((k >> 3) & 3) * 16 + lr) * 8 + (k & 7);
        Bfrag[idx] = f2bf(v);
    }
    if (threadIdx.x == 0) bias_cat[j] = bx[jj] + bh[jj];
}

// ---------------------------------------------------------------------------
// k_leafpre burst helpers.
// ---------------------------------------------------------------------------
template<int CB>
__device__ __forceinline__ void lp_burst(const bf16raw* __restrict__ bfbase, int wcol,
                                         bf16x8 (&bb)[16])
{
#pragma unroll
    for (int kt = 0; kt < 4; ++kt)
#pragma unroll
        for (int j = 0; j < 4; ++j)
            bb[kt * 4 + j] = *(const bf16x8*)(bfbase +
                    (long)(((CB * 8 + (wcol >> 4) + j) * 8 + kt) * 512));
}

__device__ __forceinline__ void lp_mfma_all(const bf16raw* __restrict__ sA, int wrow,
                                            int lrow, int lquad,
                                            bf16x8 (&bb)[16], f32x4 (&acc)[4][4])
{
#pragma unroll
    for (int kt = 0; kt < 4; ++kt) {
        bf16x8 af[4];
#pragma unroll
        for (int i = 0; i < 4; ++i)
            af[i] = *(const bf16x8*)&sA[(wrow + i * 16 + lrow) * 136 + kt * 32 + lquad * 8];
#pragma unroll
        for (int i = 0; i < 4; ++i)
#pragma unroll
            for (int j = 0; j < 4; ++j)
                acc[i][j] = __builtin_amdgcn_mfma_f32_16x16x32_bf16(af[i], bb[kt * 4 + j], acc[i][j], 0, 0, 0);
    }
}

template<int CB>
__device__ __forceinline__ void lp_rungemm(const bf16raw* __restrict__ sA,
                                           const bf16raw* __restrict__ bfbase,
                                           int wrow, int wcol, int lrow, int lquad,
                                           f32x4 (&acc)[4][4])
{
#pragma unroll
    for (int i = 0; i < 4; i++)
#pragma unroll
        for (int j = 0; j < 4; j++) acc[i][j] = (f32x4){0.f, 0.f, 0.f, 0.f};
    bf16x8 bb[16];
    lp_burst<CB>(bfbase, wcol, bb);
    SB();
    lp_mfma_all(sA, wrow, lrow, lquad, bb, acc);
}

// ---------------------------------------------------------------------------
// k_level half-burst helpers.  Wave w: coltiles w*2, w*2+1.
// PASS: 0=i, 1=u, 2=f1, 3=f2, 4=o.  Bfrag gate index per burst: i=0,u=1,f=3,o=2.
// ---------------------------------------------------------------------------
template<int G, int H>
__device__ __forceinline__ void load8(const bf16raw* __restrict__ bfbase, int w,
                                      bf16x8 (&bb)[8])
{
#pragma unroll
    for (int kt2 = 0; kt2 < 4; ++kt2)
#pragma unroll
        for (int jj = 0; jj < 2; ++jj)
            bb[kt2 * 2 + jj] = *(const bf16x8*)(bfbase +
                    (long)(((G * 8 + w * 2 + jj) * 8 + H * 4 + kt2) * 512));
}

// A-ktile map: i/u/o over [x|hs] (0..7); f1 H1 -> h1 (8..11); f2 H1 -> h2 (12..15).
template<int PASS, int H>
__device__ __forceinline__ void mfma8(const bf16raw* __restrict__ sA, int lrow, int lquad,
                                      bf16x8 (&bb)[8], f32x4 (&acc)[2][2])
{
    constexpr int base = (PASS == 2) ? (H ? 8 : 0)
                       : (PASS == 3) ? (H ? 12 : 0)
                       : H * 4;
#pragma unroll
    for (int kt2 = 0; kt2 < 4; ++kt2) {
        bf16x8 af[2];
#pragma unroll
        for (int i = 0; i < 2; ++i)
            af[i] = *(const bf16x8*)&sA[(i * 16 + lrow) * SAW + (base + kt2) * 32 + lquad * 8];
#pragma unroll
        for (int jj = 0; jj < 2; ++jj)
#pragma unroll
            for (int i = 0; i < 2; ++i)
                acc[i][jj] = __builtin_amdgcn_mfma_f32_16x16x32_bf16(af[i], bb[kt2 * 2 + jj], acc[i][jj], 0, 0, 0);
    }
}

// ---------------------------------------------------------------------------
// k_leafpre: per-vocab leaf tables (h, c, logits, lse).
// ---------------------------------------------------------------------------
__global__ __launch_bounds__(256, 2) void k_leafpre(
    const bf16raw* __restrict__ embeds_bf,
    const bf16raw* __restrict__ Bfrag, const float* __restrict__ bias_cat,
    const float* __restrict__ Wout, const float* __restrict__ bout,
    bf16raw* __restrict__ hc_leaf, float* __restrict__ lossv6, int vbase, int nv)
{
    vbase += blockIdx.x * 128;
    nv -= vbase;
    if (nv > 128) nv = 128;
    if (nv <= 0) return;

    __shared__ __align__(16) bf16raw sA[128 * 136];
    __shared__ __align__(16) bf16raw sT[128 * 136];
    __shared__ float sWout[5 * 128];

    const int t = threadIdx.x;
    for (int i = t; i < 640; i += 256) sWout[i] = Wout[i];

    {
        const int row = t >> 1;
        const int half = (t & 1) * 64;
        const int arow = (row < nv) ? row : 0;
        const bf16raw* ax = embeds_bf + (long)(vbase + arow) * 128;
#pragma unroll
        for (int s = 0; s < 8; ++s)
            *(short8*)&sA[row * 136 + half + s * 8] = *(const short8*)(ax + half + s * 8);
    }

    const int lane = t & 63;
    const int w = t >> 6;
    const int wrow = (w >> 1) * 64;
    const int wcol = (w & 1) * 64;
    const int lrow = lane & 15;
    const int lquad = lane >> 4;

    __syncthreads();

    const bf16raw* bfbase = Bfrag + (long)lane * 8;

    float tval[4][4][4];
    f32x4 acc[4][4];

    // ---- i gate ----
    lp_rungemm<0>(sA, bfbase, wrow, wcol, lrow, lquad, acc);
#pragma unroll
    for (int i = 0; i < 4; i++)
#pragma unroll
        for (int jj = 0; jj < 4; jj++) {
            const float b = bias_cat[wcol + jj * 16 + lrow];
#pragma unroll
            for (int r = 0; r < 4; r++) tval[i][jj][r] = sigm(acc[i][jj][r] + b);
        }
    // ---- u gate: tval = c = i*u ----
    lp_rungemm<1>(sA, bfbase, wrow, wcol, lrow, lquad, acc);
#pragma unroll
    for (int i = 0; i < 4; i++)
#pragma unroll
        for (int jj = 0; jj < 4; jj++) {
            const float b = bias_cat[128 + wcol + jj * 16 + lrow];
#pragma unroll
            for (int r = 0; r < 4; r++) tval[i][jj][r] *= fast_tanh(acc[i][jj][r] + b);
        }
    // write c tile, keep tanh(c) in regs
#pragma unroll
    for (int i = 0; i < 4; i++)
#pragma unroll
        for (int jj = 0; jj < 4; jj++)
#pragma unroll
            for (int r = 0; r < 4; r++) {
                const int m = wrow + i * 16 + lquad * 4 + r;
                const int j = wcol + jj * 16 + lrow;
                sT[m * 136 + j] = f2bf(tval[i][jj][r]);
            }
#pragma unroll
    for (int i = 0; i < 4; i++)
#pragma unroll
        for (int jj = 0; jj < 4; jj++)
#pragma unroll
            for (int r = 0; r < 4; r++) tval[i][jj][r] = fast_tanh(tval[i][jj][r]);
    __syncthreads();
#pragma unroll
    for (int s = 0; s < 8; ++s) {
        int ci = t + 256 * s;
        int row = ci >> 4, c8 = (ci & 15) * 8;
        if (row < nv)
            *(short8*)(hc_leaf + (long)(vbase + row) * 256 + 128 + c8) = *(const short8*)&sT[row * 136 + c8];
    }
    // ---- o gate: h = sigm(o)*tanh(c) ----
    lp_rungemm<2>(sA, bfbase, wrow, wcol, lrow, lquad, acc);
    __syncthreads();
#pragma unroll
    for (int i = 0; i < 4; i++)
#pragma unroll
        for (int jj = 0; jj < 4; jj++) {
            const float b = bias_cat[256 + wcol + jj * 16 + lrow];
#pragma unroll
            for (int r = 0; r < 4; r++) {
                const int m = wrow + i * 16 + lquad * 4 + r;
                const int j = wcol + jj * 16 + lrow;
                sT[m * 136 + j] = f2bf(sigm(acc[i][jj][r] + b) * tval[i][jj][r]);
            }
        }
    __syncthreads();
#pragma unroll
    for (int s = 0; s < 8; ++s) {
        int ci = t + 256 * s;
        int row = ci >> 4, c8 = (ci & 15) * 8;
        if (row < nv)
            *(short8*)(hc_leaf + (long)(vbase + row) * 256 + c8) = *(const short8*)&sT[row * 136 + c8];
    }
    // logits + lse per vocab row (vectorized)
    {
        const int row = t >> 1, half = t & 1;
        float p[5] = {0.f, 0.f, 0.f, 0.f, 0.f};
        const bf16raw* rp = &sT[row * 136 + half * 64];
#pragma unroll
        for (int s = 0; s < 8; ++s) {
            short8 v = *(const short8*)(rp + s * 8);
#pragma unroll
            for (int e = 0; e < 8; ++e) {
                float hv = bf2f((bf16raw)(unsigned short)v[e]);
#pragma unroll
                for (int l = 0; l < 5; l++) p[l] += hv * sWout[l * 128 + half * 64 + s * 8 + e];
            }
        }
#pragma unroll
        for (int l = 0; l < 5; l++) p[l] += __shfl_down(p[l], 1);
        if (half == 0 && row < nv) {
            float lg[5], mx = -1e30f;
#pragma unroll
            for (int l = 0; l < 5; l++) {
                lg[l] = p[l] + bout[l];
                mx = fmaxf(mx, lg[l]);
            }
            float se = 0.f;
#pragma unroll
            for (int l = 0; l < 5; l++) se += __expf(lg[l] - mx);
            float lse = __logf(se) + mx;
            float* dst = lossv6 + (long)(vbase + row) * 6;
#pragma unroll
            for (int l = 0; l < 5; l++) dst[l] = lg[l];
            dst[5] = lse;
        }
    }
}

// ---------------------------------------------------------------------------
// k_level32: one level chunk of 32 nodes.  Fold-after-pass design: each
// gate's accumulator folds into the running cell state immediately, so only
// acc[2][2] + stash are live -> (256,3) occupancy.  Loss handled by k_loss.
// ---------------------------------------------------------------------------
__global__ __launch_bounds__(256, 3) void k_level32(
    const bf16raw* __restrict__ embeds_bf, const int* __restrict__ words,
    bf16raw* __restrict__ h_all, bf16raw* __restrict__ c_all,
    const bf16raw* __restrict__ hc_leaf,
    const bf16raw* __restrict__ Bfrag, const float* __restrict__ bias_cat,
    int off, int nm, int leafkids)
{
    __shared__ __align__(16) bf16raw sA[32 * SAW];
    __shared__ __align__(16) bf16raw sCT[64 * 136];

    const int t = threadIdx.x;
    const int m0 = blockIdx.x * 32;

    // ---- stage A tile [x|hs|h1|h2]: 8 threads/row ----
    {
        const int row = t >> 3;
        const int co = (t & 7) * 8;
        int mm = m0 + row; if (mm >= nm) mm = nm - 1;
        const long g = (long)off + mm;
        const bf16raw* px = embeds_bf + (long)words[g] * 128;
        const bf16raw *p1, *p2;
        if (leafkids) {
            p1 = hc_leaf + (long)words[2 * g + 1] * 256;
            p2 = hc_leaf + (long)words[2 * g + 2] * 256;
        } else {
            p1 = h_all + (2 * g + 1) * 128;
            p2 = h_all + (2 * g + 2) * 128;
        }
        short8 vx0 = *(const short8*)(px + co);
        short8 vx1 = *(const short8*)(px + 64 + co);
        short8 h10 = *(const short8*)(p1 + co);
        short8 h11 = *(const short8*)(p1 + 64 + co);
        short8 h20 = *(const short8*)(p2 + co);
        short8 h21 = *(const short8*)(p2 + 64 + co);
        short8 hs0, hs1;
#pragma unroll
        for (int e = 0; e < 8; ++e) {
            hs0[e] = (short)f2bf(bf2f((bf16raw)(unsigned short)h10[e]) +
                                 bf2f((bf16raw)(unsigned short)h20[e]));
            hs1[e] = (short)f2bf(bf2f((bf16raw)(unsigned short)h11[e]) +
                                 bf2f((bf16raw)(unsigned short)h21[e]));
        }
        *(short8*)&sA[row * SAW + co]        = vx0;
        *(short8*)&sA[row * SAW + 64 + co]   = vx1;
        *(short8*)&sA[row * SAW + 128 + co]  = hs0;
        *(short8*)&sA[row * SAW + 192 + co]  = hs1;
        *(short8*)&sA[row * SAW + 256 + co]  = h10;
        *(short8*)&sA[row * SAW + 320 + co]  = h11;
        *(short8*)&sA[row * SAW + 384 + co]  = h20;
        *(short8*)&sA[row * SAW + 448 + co]  = h21;
    }
    // ---- stage children c: slot = 2*mlocal + childIdx ----
    {
        const int slot = t >> 2;
        const int cc8 = (t & 3) * 8;
        int mm = m0 + (slot >> 1); if (mm >= nm) mm = nm - 1;
        const long g = (long)off + mm;
        const long cg = 2 * g + 1 + (slot & 1);
        const bf16raw* pc = leafkids ? (hc_leaf + (long)words[cg] * 256 + 128)
                                     : (c_all + cg * 128);
#pragma unroll
        for (int s = 0; s < 4; ++s)
            *(short8*)&sCT[slot * 136 + s * 32 + cc8] = *(const short8*)(pc + s * 32 + cc8);
    }

    const int lane = t & 63;
    const int w = t >> 6;
    const int lrow = lane & 15;
    const int lquad = lane >> 4;

    // bias preload (gate order 0=i,1=u,2=o,3=f)
    float bias[4][2];
#pragma unroll
    for (int g = 0; g < 4; ++g)
#pragma unroll
        for (int jj = 0; jj < 2; ++jj)
            bias[g][jj] = bias_cat[g * 128 + w * 32 + jj * 16 + lrow];

    __syncthreads();   // A tile + children staged

    const bf16raw* bfbase = Bfrag + (long)lane * 8;

    f32x4 acc[2][2];
    float si[2][2][4];   // sigm(i) stash
    float cc[2][2][4];   // running c
    float hh[2][2][4];   // final h
    bf16x8 bbA[8], bbB[8];

#define ZACC() { _Pragma("unroll") for (int i_ = 0; i_ < 2; ++i_) \
                 _Pragma("unroll") for (int j_ = 0; j_ < 2; ++j_) \
                     acc[i_][j_] = (f32x4){0.f, 0.f, 0.f, 0.f}; }

    load8<0, 0>(bfbase, w, bbA);
    load8<0, 1>(bfbase, w, bbB);
    SB();
    ZACC();
    mfma8<0, 0>(sA, lrow, lquad, bbA, acc); SB();
    load8<1, 0>(bfbase, w, bbA); SB();
    mfma8<0, 1>(sA, lrow, lquad, bbB, acc); SB();
    load8<1, 1>(bfbase, w, bbB); SB();
    // fold i
#pragma unroll
    for (int i = 0; i < 2; ++i)
#pragma unroll
        for (int jj = 0; jj < 2; ++jj)
#pragma unroll
            for (int r = 0; r < 4; ++r)
                si[i][jj][r] = sigm(acc[i][jj][r] + bias[0][jj]);
    ZACC();
    mfma8<1, 0>(sA, lrow, lquad, bbA, acc); SB();
    load8<3, 0>(bfbase, w, bbA); SB();
    mfma8<1, 1>(sA, lrow, lquad, bbB, acc); SB();
    load8<3, 1>(bfbase, w, bbB); SB();
    // fold u: cc = sigm(i) * tanh(u)
#pragma unroll
    for (int i = 0; i < 2; ++i)
#pragma unroll
        for (int jj = 0; jj < 2; ++jj)
#pragma unroll
            for (int r = 0; r < 4; ++r)
                cc[i][jj][r] = si[i][jj][r] * fast_tanh(acc[i][jj][r] + bias[1][jj]);
    ZACC();
    mfma8<2, 0>(sA, lrow, lquad, bbA, acc);
    mfma8<2, 1>(sA, lrow, lquad, bbB, acc);
    SB();
    // fold f1: cc += sigm(f1) * c1
#pragma unroll
    for (int i = 0; i < 2; ++i)
#pragma unroll
        for (int jj = 0; jj < 2; ++jj) {
            const int j = w * 32 + jj * 16 + lrow;
#pragma unroll
            for (int r = 0; r < 4; ++r) {
                const int m = i * 16 + lquad * 4 + r;
                cc[i][jj][r] += sigm(acc[i][jj][r] + bias[3][jj]) * bf2f(sCT[(2 * m) * 136 + j]);
            }
        }
    ZACC();
    mfma8<3, 0>(sA, lrow, lquad, bbA, acc);
    mfma8<3, 1>(sA, lrow, lquad, bbB, acc);
    SB();
    load8<2, 0>(bfbase, w, bbA);
    load8<2, 1>(bfbase, w, bbB);
    SB();
    // fold f2: cc += sigm(f2) * c2   (overlaps o-burst latency)
#pragma unroll
    for (int i = 0; i < 2; ++i)
#pragma unroll
        for (int jj = 0; jj < 2; ++jj) {
            const int j = w * 32 + jj * 16 + lrow;
#pragma unroll
            for (int r = 0; r < 4; ++r) {
                const int m = i * 16 + lquad * 4 + r;
                cc[i][jj][r] += sigm(acc[i][jj][r] + bias[3][jj]) * bf2f(sCT[(2 * m + 1) * 136 + j]);
            }
        }
    ZACC();
    mfma8<4, 0>(sA, lrow, lquad, bbA, acc);
    mfma8<4, 1>(sA, lrow, lquad, bbB, acc);
    SB();
    // fold o: hh = sigm(o) * tanh(cc)
#pragma unroll
    for (int i = 0; i < 2; ++i)
#pragma unroll
        for (int jj = 0; jj < 2; ++jj)
#pragma unroll
            for (int r = 0; r < 4; ++r)
                hh[i][jj][r] = sigm(acc[i][jj][r] + bias[2][jj]) * fast_tanh(cc[i][jj][r]);
#undef ZACC

    __syncthreads();   // all sCT child reads done

    // ---- write c (rows 0..31) / h (rows 32..63) tiles into sCT ----
#pragma unroll
    for (int i = 0; i < 2; ++i)
#pragma unroll
        for (int jj = 0; jj < 2; ++jj) {
            const int j = w * 32 + jj * 16 + lrow;
#pragma unroll
            for (int r = 0; r < 4; ++r) {
                const int m = i * 16 + lquad * 4 + r;
                sCT[m * 136 + j] = f2bf(cc[i][jj][r]);
                sCT[(32 + m) * 136 + j] = f2bf(hh[i][jj][r]);
            }
        }
    __syncthreads();

    // ---- coalesced flush ----
#pragma unroll
    for (int q = 0; q < 4; ++q) {
        int ci = t + 256 * q;
        int row = ci >> 4;
        int c8 = (ci & 15) * 8;
        int m = row & 31;
        if (m0 + m < nm) {
            bf16raw* dst = (row < 32) ? c_all : h_all;
            *(short8*)(dst + ((long)off + m0 + m) * 128 + c8) = *(const short8*)&sCT[row * 136 + c8];
        }
    }
}

// ---------------------------------------------------------------------------
// k_loss: one pass over all internal nodes.  2 threads/node; logits via
// Wout GEMV from h_all; level-16 nodes add their leaf children's terms;
// root writes out[0..4]; per-block partial into partials.
// ---------------------------------------------------------------------------
__global__ __launch_bounds__(256) void k_loss(
    const bf16raw* __restrict__ h_all, const int* __restrict__ words,
    const int* __restrict__ labels, const float* __restrict__ lossv6,
    const float* __restrict__ Wout, const float* __restrict__ bout,
    float* __restrict__ partials, float* __restrict__ out)
{
    __shared__ float sWout[640];
    __shared__ float red[128];
    const int t = threadIdx.x;
    for (int i = t; i < 640; i += 256) sWout[i] = Wout[i];

    const int row = t >> 1, half = t & 1;
    const long g = (long)blockIdx.x * 128 + row;
    const bool valid = g < NINT;
    const long gg = valid ? g : 0;
    __syncthreads();

    float p[5] = {0.f, 0.f, 0.f, 0.f, 0.f};
    const bf16raw* hp = h_all + gg * 128 + half * 64;
#pragma unroll
    for (int s = 0; s < 8; ++s) {
        short8 v = *(const short8*)(hp + s * 8);
#pragma unroll
        for (int e = 0; e < 8; ++e) {
            float hv = bf2f((bf16raw)(unsigned short)v[e]);
#pragma unroll
            for (int l = 0; l < 5; l++) p[l] += hv * sWout[l * 128 + half * 64 + s * 8 + e];
        }
    }
#pragma unroll
    for (int l = 0; l < 5; l++) p[l] += __shfl_down(p[l], 1);

    float lossNode = 0.f;
    if (half == 0 && valid) {
        float lg[5], mx = -1e30f;
#pragma unroll
        for (int l = 0; l < 5; l++) {
            lg[l] = p[l] + bout[l];
            mx = fmaxf(mx, lg[l]);
        }
        float se = 0.f;
#pragma unroll
        for (int l = 0; l < 5; l++) se += __expf(lg[l] - mx);
        float lse = __logf(se) + mx;
        lossNode = lse - lg[labels[gg]];
        if (gg >= LEAF_OFF) {   // level-16 node: add leaf children terms
            const float* lv1 = lossv6 + (long)words[2 * gg + 1] * 6;
            const float* lv2 = lossv6 + (long)words[2 * gg + 2] * 6;
            lossNode += (lv1[5] - lv1[labels[2 * gg + 1]])
                      + (lv2[5] - lv2[labels[2 * gg + 2]]);
        }
        if (gg == 0) {
#pragma unroll
            for (int l = 0; l < 5; l++) out[l] = lg[l] - lse;
        }
    }
    if (half == 0) red[row] = lossNode;
    __syncthreads();
    if (t < 64) {
        float s = red[t] + red[t + 64];
#pragma unroll
        for (int d = 32; d > 0; d >>= 1) s += __shfl_down(s, d);
        if (t == 0) atomicAdd(&partials[blockIdx.x & 1023], s);
    }
}

__global__ __launch_bounds__(256) void k3_reduce(const float* __restrict__ partials,
                                                 float* __restrict__ out)
{
    const int t = threadIdx.x;
    float s = 0.f;
    for (int i = t; i < 1024; i += 256) s += partials[i];
#pragma unroll
    for (int d = 32; d > 0; d >>= 1) s += __shfl_down(s, d);
    __shared__ float red[4];
    if ((t & 63) == 0) red[t >> 6] = s;
    __syncthreads();
    if (t == 0) out[5] = red[0] + red[1] + red[2] + red[3];
}

// ---------------------------------------------------------------------------
extern "C" void kernel_launch(void* const* d_in, const int* in_sizes, int n_in,
                              void* d_out, int out_size, void* d_ws, size_t ws_size,
                              hipStream_t stream)
{
    const float* embeds = (const float*)d_in[0];
    const int* words = (const int*)d_in[1];
    const int* labels = (const int*)d_in[2];
    const float* Wix = (const float*)d_in[5],  *bix  = (const float*)d_in[6];
    const float* Wih = (const float*)d_in[7],  *bih  = (const float*)d_in[8];
    const float* Wfx = (const float*)d_in[9],  *bfx  = (const float*)d_in[10];
    const float* Wfh = (const float*)d_in[11], *bfh  = (const float*)d_in[12];
    const float* Wox = (const float*)d_in[13], *box_ = (const float*)d_in[14];
    const float* Woh = (const float*)d_in[15], *boh  = (const float*)d_in[16];
    const float* Wux = (const float*)d_in[17], *bux  = (const float*)d_in[18];
    const float* Wuh = (const float*)d_in[19], *buh  = (const float*)d_in[20];
    const float* Wout = (const float*)d_in[21], *bout = (const float*)d_in[22];
    float* out = (float*)d_out;

    char* ws = (char*)d_ws;
    const size_t treeElems = (size_t)NINT * 128;
    bf16raw* h_all = (bf16raw*)ws;
    bf16raw* c_all = h_all + treeElems;
    bf16raw* embeds_bf = c_all + treeElems;
    bf16raw* Bfrag = embeds_bf + (size_t)NVOCAB * 128;
    bf16raw* hc_leaf = Bfrag + 4 * 8 * 8 * 512;          // 256KB dedup B
    float* lossv6 = (float*)(hc_leaf + (size_t)NVOCAB * 256);
    float* bias_cat = lossv6 + (size_t)NVOCAB * 6;
    float* partials = bias_cat + 512;

    k_prep_embeds<<<(NVOCAB * 128 / 4 + 255) / 256, 256, 0, stream>>>(
        embeds, embeds_bf, NVOCAB * 128 / 4);
    k_prep_bcat<<<512, 128, 0, stream>>>(Wix, bix, Wih, bih, Wfx, bfx, Wfh, bfh,
                                         Wox, box_, Woh, boh, Wux, bux, Wuh, buh,
                                         Bfrag, bias_cat);
    hipMemsetAsync(partials, 0, 1024 * sizeof(float), stream);

    k_leafpre<<<(NVOCAB + 127) / 128, 256, 0, stream>>>(
        embeds_bf, Bfrag, bias_cat, Wout, bout, hc_leaf, lossv6, 0, NVOCAB);

    for (int l = DEPTH - 2; l >= 0; --l) {
        const int n = 1 << l;
        k_level32<<<dim3((n + 31) / 32), 256, 0, stream>>>(
            embeds_bf, words, h_all, c_all, hc_leaf, Bfrag, bias_cat,
            n - 1, n, (l == DEPTH - 2) ? 1 : 0);
    }

    k_loss<<<(NINT + 127) / 128, 256, 0, stream>>>(
        h_all, words, labels, lossv6, Wout, bout, partials, out);
    k3_reduce<<<1, 256, 0, stream>>>(partials, out);
}

// Round 10
// 372.180 us; speedup vs baseline: 1.1623x; 1.0156x over previous
//
#include <hip/hip_runtime.h>
#include <math.h>

#define DEPTH 18
#define NINT ((1 << (DEPTH - 1)) - 1)      // internal nodes = 131071
#define LEAF_OFF ((1 << (DEPTH - 2)) - 1)  // first level-16 node = 65535
#define NVOCAB 50000
#define SAW 520                             // sA row stride: [x|hs|h1|h2] + pad
#define KTS 9                               // Bfrag ktile stride (8 used + 1 pad; kills pow2 aliasing)

typedef unsigned short bf16raw;
typedef __bf16 bf16x8 __attribute__((ext_vector_type(8)));
typedef float f32x4 __attribute__((ext_vector_type(4)));
typedef short short8 __attribute__((ext_vector_type(8)));

__device__ __forceinline__ float sigm(float x) { return 1.0f / (1.0f + __expf(-x)); }
// NaN-safe fast tanh (saturates correctly at +-inf).
__device__ __forceinline__ float fast_tanh(float x) {
    float t = __expf(2.0f * x);
    return 1.0f - 2.0f / (t + 1.0f);
}

__device__ __forceinline__ float bf2f(bf16raw u) {
    union { unsigned int i; float f; } v;
    v.i = ((unsigned int)u) << 16;
    return v.f;
}
__device__ __forceinline__ bf16raw f2bf(float f) {
    union { float f; unsigned int i; } v;
    v.f = f;
    unsigned int r = v.i + 0x7FFFu + ((v.i >> 16) & 1u);  // RNE
    return (bf16raw)(r >> 16);
}

#define SB() __builtin_amdgcn_sched_barrier(0)

// ---------------------------------------------------------------------------
__global__ __launch_bounds__(256) void k_prep_embeds(const float* __restrict__ src,
                                                     bf16raw* __restrict__ dst, int n4)
{
    int i = blockIdx.x * blockDim.x + threadIdx.x;
    if (i < n4) {
        float4 v = ((const float4*)src)[i];
        ushort4 o;
        o.x = f2bf(v.x); o.y = f2bf(v.y); o.z = f2bf(v.z); o.w = f2bf(v.w);
        ((ushort4*)dst)[i] = o;
    }
}

// ---------------------------------------------------------------------------
// Bfrag: fragment-linear, dedup'd B.  Gates: 0=i, 1=u, 2=o, 3=f; each gate
// [Wx|Wh], K=256 (8 ktiles, stride KTS=9 to avoid power-of-2 strides).
//   Bfrag[(((gate*8+coltile)*KTS+ktile)*64 + lane)*8 + e]
//   coltile=col>>4, lane=((k>>3)&3)*16+(col&15), ktile=k>>5, e=k&7.
// Wave B-fragment load = 64 consecutive 16B chunks = one coalesced 1KB txn.
// ---------------------------------------------------------------------------
__global__ __launch_bounds__(128) void k_prep_bcat(
    const float* __restrict__ Wix, const float* __restrict__ bix,
    const float* __restrict__ Wih, const float* __restrict__ bih,
    const float* __restrict__ Wfx, const float* __restrict__ bfx,
    const float* __restrict__ Wfh, const float* __restrict__ bfh,
    const float* __restrict__ Wox, const float* __restrict__ box_,
    const float* __restrict__ Woh, const float* __restrict__ boh,
    const float* __restrict__ Wux, const float* __restrict__ bux,
    const float* __restrict__ Wuh, const float* __restrict__ buh,
    bf16raw* __restrict__ Bfrag, float* __restrict__ bias_cat)
{
    const int j = blockIdx.x;        // 0..511 = gate*128 + col
    const int gate = j >> 7, jj = j & 127;
    const float *Wx, *Wh, *bx, *bh;
    switch (gate) {
        case 0: Wx = Wix; Wh = Wih; bx = bix;  bh = bih; break;
        case 1: Wx = Wux; Wh = Wuh; bx = bux;  bh = buh; break;
        case 2: Wx = Wox; Wh = Woh; bx = box_; bh = boh; break;
        default: Wx = Wfx; Wh = Wfh; bx = bfx; bh = bfh; break;
    }
    const int coltile = (j >> 4) & 7, lr = j & 15;
    for (int k = threadIdx.x; k < 256; k += blockDim.x) {
        float v = (k < 128) ? Wx[jj * 128 + k] : Wh[jj * 128 + (k - 128)];
        const int idx = (((gate * 8 + coltile) * KTS + (k >> 5)) * 64
                         + ((k >> 3) & 3) * 16 + lr) * 8 + (k & 7);
        Bfrag[idx] = f2bf(v);
    }
    if (threadIdx.x == 0) bias_cat[j] = bx[jj] + bh[jj];
}

// ---------------------------------------------------------------------------
// k_leafpre burst helpers (64-row variant: acc[2][4], x-part ktiles 0..3).
// ---------------------------------------------------------------------------
template<int CB>
__device__ __forceinline__ void lp_burst(const bf16raw* __restrict__ bfbase, int wcol,
                                         bf16x8 (&bb)[16])
{
#pragma unroll
    for (int kt = 0; kt < 4; ++kt)
#pragma unroll
        for (int j = 0; j < 4; ++j)
            bb[kt * 4 + j] = *(const bf16x8*)(bfbase +
                    (long)(((CB * 8 + (wcol >> 4) + j) * KTS + kt) * 512));
}

__device__ __forceinline__ void lp_mfma_all(const bf16raw* __restrict__ sA, int wrow,
                                            int lrow, int lquad,
                                            bf16x8 (&bb)[16], f32x4 (&acc)[2][4])
{
#pragma unroll
    for (int kt = 0; kt < 4; ++kt) {
        bf16x8 af[2];
#pragma unroll
        for (int i = 0; i < 2; ++i)
            af[i] = *(const bf16x8*)&sA[(wrow + i * 16 + lrow) * 136 + kt * 32 + lquad * 8];
#pragma unroll
        for (int i = 0; i < 2; ++i)
#pragma unroll
            for (int j = 0; j < 4; ++j)
                acc[i][j] = __builtin_amdgcn_mfma_f32_16x16x32_bf16(af[i], bb[kt * 4 + j], acc[i][j], 0, 0, 0);
    }
}

template<int CB>
__device__ __forceinline__ void lp_rungemm(const bf16raw* __restrict__ sA,
                                           const bf16raw* __restrict__ bfbase,
                                           int wrow, int wcol, int lrow, int lquad,
                                           f32x4 (&acc)[2][4])
{
#pragma unroll
    for (int i = 0; i < 2; i++)
#pragma unroll
        for (int j = 0; j < 4; j++) acc[i][j] = (f32x4){0.f, 0.f, 0.f, 0.f};
    bf16x8 bb[16];
    lp_burst<CB>(bfbase, wcol, bb);
    SB();
    lp_mfma_all(sA, wrow, lrow, lquad, bb, acc);
}

// ---------------------------------------------------------------------------
// k_level half-burst helpers.  Wave w: coltiles w*2, w*2+1.
// PASS: 0=i, 1=u, 2=f1, 3=f2, 4=o.  Bfrag gate index per burst: i=0,u=1,f=3,o=2.
// ---------------------------------------------------------------------------
template<int G, int H>
__device__ __forceinline__ void load8(const bf16raw* __restrict__ bfbase, int w,
                                      bf16x8 (&bb)[8])
{
#pragma unroll
    for (int kt2 = 0; kt2 < 4; ++kt2)
#pragma unroll
        for (int jj = 0; jj < 2; ++jj)
            bb[kt2 * 2 + jj] = *(const bf16x8*)(bfbase +
                    (long)(((G * 8 + w * 2 + jj) * KTS + H * 4 + kt2) * 512));
}

// A-ktile map: i/u/o over [x|hs] (0..7); f1 H1 -> h1 (8..11); f2 H1 -> h2 (12..15).
template<int PASS, int H>
__device__ __forceinline__ void mfma8(const bf16raw* __restrict__ sA, int lrow, int lquad,
                                      bf16x8 (&bb)[8], f32x4 (&acc)[2][2])
{
    constexpr int base = (PASS == 2) ? (H ? 8 : 0)
                       : (PASS == 3) ? (H ? 12 : 0)
                       : H * 4;
#pragma unroll
    for (int kt2 = 0; kt2 < 4; ++kt2) {
        bf16x8 af[2];
#pragma unroll
        for (int i = 0; i < 2; ++i)
            af[i] = *(const bf16x8*)&sA[(i * 16 + lrow) * SAW + (base + kt2) * 32 + lquad * 8];
#pragma unroll
        for (int jj = 0; jj < 2; ++jj)
#pragma unroll
            for (int i = 0; i < 2; ++i)
                acc[i][jj] = __builtin_amdgcn_mfma_f32_16x16x32_bf16(af[i], bb[kt2 * 2 + jj], acc[i][jj], 0, 0, 0);
    }
}

// ---------------------------------------------------------------------------
// k_leafpre: per-vocab leaf tables (h, c, logits, lse).  64 rows/block,
// 782 blocks, ~37.5KB LDS, launch_bounds(256,3) -> ~3 blocks/CU = 12
// waves/CU (vs round-9's 5.5): latency-bound time scales with TLP.
// Wave w: rows (w&1)*32..+32, cols (w>>1)*64..+64.
// ---------------------------------------------------------------------------
__global__ __launch_bounds__(256, 3) void k_leafpre(
    const bf16raw* __restrict__ embeds_bf,
    const bf16raw* __restrict__ Bfrag, const float* __restrict__ bias_cat,
    const float* __restrict__ Wout, const float* __restrict__ bout,
    bf16raw* __restrict__ hc_leaf, float* __restrict__ lossv6, int nvtot)
{
    const int vbase = blockIdx.x * 64;
    int nv = nvtot - vbase;
    if (nv > 64) nv = 64;
    if (nv <= 0) return;

    __shared__ __align__(16) bf16raw sA[64 * 136];
    __shared__ __align__(16) bf16raw sT[64 * 136];
    __shared__ float sWout[5 * 128];

    const int t = threadIdx.x;
    for (int i = t; i < 640; i += 256) sWout[i] = Wout[i];

    // ---- stage A: 4 threads/row x 32 elems ----
    {
        const int row = t >> 2;              // 0..63
        const int co = (t & 3) * 32;
        const int arow = (row < nv) ? row : 0;
        const bf16raw* ax = embeds_bf + (long)(vbase + arow) * 128;
        *(short8*)&sA[row * 136 + co]      = *(const short8*)(ax + co);
        *(short8*)&sA[row * 136 + co + 8]  = *(const short8*)(ax + co + 8);
        *(short8*)&sA[row * 136 + co + 16] = *(const short8*)(ax + co + 16);
        *(short8*)&sA[row * 136 + co + 24] = *(const short8*)(ax + co + 24);
    }

    const int lane = t & 63;
    const int w = t >> 6;
    const int wrow = (w & 1) * 32;
    const int wcol = (w >> 1) * 64;
    const int lrow = lane & 15;
    const int lquad = lane >> 4;

    __syncthreads();

    const bf16raw* bfbase = Bfrag + (long)lane * 8;

    float tval[2][4][4];
    f32x4 acc[2][4];

    // ---- i gate ----
    lp_rungemm<0>(sA, bfbase, wrow, wcol, lrow, lquad, acc);
#pragma unroll
    for (int i = 0; i < 2; i++)
#pragma unroll
        for (int jj = 0; jj < 4; jj++) {
            const float b = bias_cat[wcol + jj * 16 + lrow];
#pragma unroll
            for (int r = 0; r < 4; r++) tval[i][jj][r] = sigm(acc[i][jj][r] + b);
        }
    // ---- u gate: tval = c = i*u ----
    lp_rungemm<1>(sA, bfbase, wrow, wcol, lrow, lquad, acc);
#pragma unroll
    for (int i = 0; i < 2; i++)
#pragma unroll
        for (int jj = 0; jj < 4; jj++) {
            const float b = bias_cat[128 + wcol + jj * 16 + lrow];
#pragma unroll
            for (int r = 0; r < 4; r++) tval[i][jj][r] *= fast_tanh(acc[i][jj][r] + b);
        }
    // write c tile, keep tanh(c) in regs
#pragma unroll
    for (int i = 0; i < 2; i++)
#pragma unroll
        for (int jj = 0; jj < 4; jj++)
#pragma unroll
            for (int r = 0; r < 4; r++) {
                const int m = wrow + i * 16 + lquad * 4 + r;
                const int j = wcol + jj * 16 + lrow;
                sT[m * 136 + j] = f2bf(tval[i][jj][r]);
            }
#pragma unroll
    for (int i = 0; i < 2; i++)
#pragma unroll
        for (int jj = 0; jj < 4; jj++)
#pragma unroll
            for (int r = 0; r < 4; r++) tval[i][jj][r] = fast_tanh(tval[i][jj][r]);
    __syncthreads();
    // flush c: 64 rows x 16 chunks = 1024 chunks / 256 thr = 4 each
#pragma unroll
    for (int s = 0; s < 4; ++s) {
        int ci = t + 256 * s;
        int row = ci >> 4, c8 = (ci & 15) * 8;
        if (row < nv)
            *(short8*)(hc_leaf + (long)(vbase + row) * 256 + 128 + c8) = *(const short8*)&sT[row * 136 + c8];
    }
    // ---- o gate: h = sigm(o)*tanh(c) ----
    lp_rungemm<2>(sA, bfbase, wrow, wcol, lrow, lquad, acc);
    __syncthreads();
#pragma unroll
    for (int i = 0; i < 2; i++)
#pragma unroll
        for (int jj = 0; jj < 4; jj++) {
            const float b = bias_cat[256 + wcol + jj * 16 + lrow];
#pragma unroll
            for (int r = 0; r < 4; r++) {
                const int m = wrow + i * 16 + lquad * 4 + r;
                const int j = wcol + jj * 16 + lrow;
                sT[m * 136 + j] = f2bf(sigm(acc[i][jj][r] + b) * tval[i][jj][r]);
            }
        }
    __syncthreads();
    // flush h
#pragma unroll
    for (int s = 0; s < 4; ++s) {
        int ci = t + 256 * s;
        int row = ci >> 4, c8 = (ci & 15) * 8;
        if (row < nv)
            *(short8*)(hc_leaf + (long)(vbase + row) * 256 + c8) = *(const short8*)&sT[row * 136 + c8];
    }
    // logits + lse: 4 threads/row, scalar reads (r7 form)
    {
        const int row = t >> 2, q = t & 3;
        float p[5] = {0.f, 0.f, 0.f, 0.f, 0.f};
        for (int k0 = 0; k0 < 32; ++k0) {
            const int k = q * 32 + k0;
            float hv = bf2f(sT[row * 136 + k]);
#pragma unroll
            for (int l = 0; l < 5; l++) p[l] += hv * sWout[l * 128 + k];
        }
#pragma unroll
        for (int l = 0; l < 5; l++) {
            p[l] += __shfl_down(p[l], 2);
            p[l] += __shfl_down(p[l], 1);
        }
        if (q == 0 && row < nv) {
            float lg[5], mx = -1e30f;
#pragma unroll
            for (int l = 0; l < 5; l++) {
                lg[l] = p[l] + bout[l];
                mx = fmaxf(mx, lg[l]);
            }
            float se = 0.f;
#pragma unroll
            for (int l = 0; l < 5; l++) se += __expf(lg[l] - mx);
            float lse = __logf(se) + mx;
            float* dst = lossv6 + (long)(vbase + row) * 6;
#pragma unroll
            for (int l = 0; l < 5; l++) dst[l] = lg[l];
            dst[5] = lse;
        }
    }
}

// ---------------------------------------------------------------------------
// k_level32: one level chunk of 32 nodes.  Fold-after-pass design (r8/r9),
// unchanged except Bfrag KTS=9 stride (A/B test for pow2-stride aliasing).
// ---------------------------------------------------------------------------
__global__ __launch_bounds__(256, 3) void k_level32(
    const bf16raw* __restrict__ embeds_bf, const int* __restrict__ words,
    bf16raw* __restrict__ h_all, bf16raw* __restrict__ c_all,
    const bf16raw* __restrict__ hc_leaf,
    const bf16raw* __restrict__ Bfrag, const float* __restrict__ bias_cat,
    int off, int nm, int leafkids)
{
    __shared__ __align__(16) bf16raw sA[32 * SAW];
    __shared__ __align__(16) bf16raw sCT[64 * 136];

    const int t = threadIdx.x;
    const int m0 = blockIdx.x * 32;

    // ---- stage A tile [x|hs|h1|h2]: 8 threads/row ----
    {
        const int row = t >> 3;
        const int co = (t & 7) * 8;
        int mm = m0 + row; if (mm >= nm) mm = nm - 1;
        const long g = (long)off + mm;
        const bf16raw* px = embeds_bf + (long)words[g] * 128;
        const bf16raw *p1, *p2;
        if (leafkids) {
            p1 = hc_leaf + (long)words[2 * g + 1] * 256;
            p2 = hc_leaf + (long)words[2 * g + 2] * 256;
        } else {
            p1 = h_all + (2 * g + 1) * 128;
            p2 = h_all + (2 * g + 2) * 128;
        }
        short8 vx0 = *(const short8*)(px + co);
        short8 vx1 = *(const short8*)(px + 64 + co);
        short8 h10 = *(const short8*)(p1 + co);
        short8 h11 = *(const short8*)(p1 + 64 + co);
        short8 h20 = *(const short8*)(p2 + co);
        short8 h21 = *(const short8*)(p2 + 64 + co);
        short8 hs0, hs1;
#pragma unroll
        for (int e = 0; e < 8; ++e) {
            hs0[e] = (short)f2bf(bf2f((bf16raw)(unsigned short)h10[e]) +
                                 bf2f((bf16raw)(unsigned short)h20[e]));
            hs1[e] = (short)f2bf(bf2f((bf16raw)(unsigned short)h11[e]) +
                                 bf2f((bf16raw)(unsigned short)h21[e]));
        }
        *(short8*)&sA[row * SAW + co]        = vx0;
        *(short8*)&sA[row * SAW + 64 + co]   = vx1;
        *(short8*)&sA[row * SAW + 128 + co]  = hs0;
        *(short8*)&sA[row * SAW + 192 + co]  = hs1;
        *(short8*)&sA[row * SAW + 256 + co]  = h10;
        *(short8*)&sA[row * SAW + 320 + co]  = h11;
        *(short8*)&sA[row * SAW + 384 + co]  = h20;
        *(short8*)&sA[row * SAW + 448 + co]  = h21;
    }
    // ---- stage children c: slot = 2*mlocal + childIdx ----
    {
        const int slot = t >> 2;
        const int cc8 = (t & 3) * 8;
        int mm = m0 + (slot >> 1); if (mm >= nm) mm = nm - 1;
        const long g = (long)off + mm;
        const long cg = 2 * g + 1 + (slot & 1);
        const bf16raw* pc = leafkids ? (hc_leaf + (long)words[cg] * 256 + 128)
                                     : (c_all + cg * 128);
#pragma unroll
        for (int s = 0; s < 4; ++s)
            *(short8*)&sCT[slot * 136 + s * 32 + cc8] = *(const short8*)(pc + s * 32 + cc8);
    }

    const int lane = t & 63;
    const int w = t >> 6;
    const int lrow = lane & 15;
    const int lquad = lane >> 4;

    // bias preload (gate order 0=i,1=u,2=o,3=f)
    float bias[4][2];
#pragma unroll
    for (int g = 0; g < 4; ++g)
#pragma unroll
        for (int jj = 0; jj < 2; ++jj)
            bias[g][jj] = bias_cat[g * 128 + w * 32 + jj * 16 + lrow];

    __syncthreads();   // A tile + children staged

    const bf16raw* bfbase = Bfrag + (long)lane * 8;

    f32x4 acc[2][2];
    float si[2][2][4];   // sigm(i) stash
    float cc[2][2][4];   // running c
    float hh[2][2][4];   // final h
    bf16x8 bbA[8], bbB[8];

#define ZACC() { _Pragma("unroll") for (int i_ = 0; i_ < 2; ++i_) \
                 _Pragma("unroll") for (int j_ = 0; j_ < 2; ++j_) \
                     acc[i_][j_] = (f32x4){0.f, 0.f, 0.f, 0.f}; }

    load8<0, 0>(bfbase, w, bbA);
    load8<0, 1>(bfbase, w, bbB);
    SB();
    ZACC();
    mfma8<0, 0>(sA, lrow, lquad, bbA, acc); SB();
    load8<1, 0>(bfbase, w, bbA); SB();
    mfma8<0, 1>(sA, lrow, lquad, bbB, acc); SB();
    load8<1, 1>(bfbase, w, bbB); SB();
    // fold i
#pragma unroll
    for (int i = 0; i < 2; ++i)
#pragma unroll
        for (int jj = 0; jj < 2; ++jj)
#pragma unroll
            for (int r = 0; r < 4; ++r)
                si[i][jj][r] = sigm(acc[i][jj][r] + bias[0][jj]);
    ZACC();
    mfma8<1, 0>(sA, lrow, lquad, bbA, acc); SB();
    load8<3, 0>(bfbase, w, bbA); SB();
    mfma8<1, 1>(sA, lrow, lquad, bbB, acc); SB();
    load8<3, 1>(bfbase, w, bbB); SB();
    // fold u: cc = sigm(i) * tanh(u)
#pragma unroll
    for (int i = 0; i < 2; ++i)
#pragma unroll
        for (int jj = 0; jj < 2; ++jj)
#pragma unroll
            for (int r = 0; r < 4; ++r)
                cc[i][jj][r] = si[i][jj][r] * fast_tanh(acc[i][jj][r] + bias[1][jj]);
    ZACC();
    mfma8<2, 0>(sA, lrow, lquad, bbA, acc);
    mfma8<2, 1>(sA, lrow, lquad, bbB, acc);
    SB();
    // fold f1: cc += sigm(f1) * c1
#pragma unroll
    for (int i = 0; i < 2; ++i)
#pragma unroll
        for (int jj = 0; jj < 2; ++jj) {
            const int j = w * 32 + jj * 16 + lrow;
#pragma unroll
            for (int r = 0; r < 4; ++r) {
                const int m = i * 16 + lquad * 4 + r;
                cc[i][jj][r] += sigm(acc[i][jj][r] + bias[3][jj]) * bf2f(sCT[(2 * m) * 136 + j]);
            }
        }
    ZACC();
    mfma8<3, 0>(sA, lrow, lquad, bbA, acc);
    mfma8<3, 1>(sA, lrow, lquad, bbB, acc);
    SB();
    load8<2, 0>(bfbase, w, bbA);
    load8<2, 1>(bfbase, w, bbB);
    SB();
    // fold f2: cc += sigm(f2) * c2   (overlaps o-burst latency)
#pragma unroll
    for (int i = 0; i < 2; ++i)
#pragma unroll
        for (int jj = 0; jj < 2; ++jj) {
            const int j = w * 32 + jj * 16 + lrow;
#pragma unroll
            for (int r = 0; r < 4; ++r) {
                const int m = i * 16 + lquad * 4 + r;
                cc[i][jj][r] += sigm(acc[i][jj][r] + bias[3][jj]) * bf2f(sCT[(2 * m + 1) * 136 + j]);
            }
        }
    ZACC();
    mfma8<4, 0>(sA, lrow, lquad, bbA, acc);
    mfma8<4, 1>(sA, lrow, lquad, bbB, acc);
    SB();
    // fold o: hh = sigm(o) * tanh(cc)
#pragma unroll
    for (int i = 0; i < 2; ++i)
#pragma unroll
        for (int jj = 0; jj < 2; ++jj)
#pragma unroll
            for (int r = 0; r < 4; ++r)
                hh[i][jj][r] = sigm(acc[i][jj][r] + bias[2][jj]) * fast_tanh(cc[i][jj][r]);
#undef ZACC

    __syncthreads();   // all sCT child reads done

    // ---- write c (rows 0..31) / h (rows 32..63) tiles into sCT ----
#pragma unroll
    for (int i = 0; i < 2; ++i)
#pragma unroll
        for (int jj = 0; jj < 2; ++jj) {
            const int j = w * 32 + jj * 16 + lrow;
#pragma unroll
            for (int r = 0; r < 4; ++r) {
                const int m = i * 16 + lquad * 4 + r;
                sCT[m * 136 + j] = f2bf(cc[i][jj][r]);
                sCT[(32 + m) * 136 + j] = f2bf(hh[i][jj][r]);
            }
        }
    __syncthreads();

    // ---- coalesced flush ----
#pragma unroll
    for (int q = 0; q < 4; ++q) {
        int ci = t + 256 * q;
        int row = ci >> 4;
        int c8 = (ci & 15) * 8;
        int m = row & 31;
        if (m0 + m < nm) {
            bf16raw* dst = (row < 32) ? c_all : h_all;
            *(short8*)(dst + ((long)off + m0 + m) * 128 + c8) = *(const short8*)&sCT[row * 136 + c8];
        }
    }
}

// ---------------------------------------------------------------------------
// k_loss: one pass over all internal nodes.  2 threads/node; logits via
// Wout GEMV from h_all; level-16 nodes add their leaf children's terms;
// root writes out[0..4]; per-block partial into partials.
// ---------------------------------------------------------------------------
__global__ __launch_bounds__(256) void k_loss(
    const bf16raw* __restrict__ h_all, const int* __restrict__ words,
    const int* __restrict__ labels, const float* __restrict__ lossv6,
    const float* __restrict__ Wout, const float* __restrict__ bout,
    float* __restrict__ partials, float* __restrict__ out)
{
    __shared__ float sWout[640];
    __shared__ float red[128];
    const int t = threadIdx.x;
    for (int i = t; i < 640; i += 256) sWout[i] = Wout[i];

    const int row = t >> 1, half = t & 1;
    const long g = (long)blockIdx.x * 128 + row;
    const bool valid = g < NINT;
    const long gg = valid ? g : 0;
    __syncthreads();

    float p[5] = {0.f, 0.f, 0.f, 0.f, 0.f};
    const bf16raw* hp = h_all + gg * 128 + half * 64;
#pragma unroll
    for (int s = 0; s < 8; ++s) {
        short8 v = *(const short8*)(hp + s * 8);
#pragma unroll
        for (int e = 0; e < 8; ++e) {
            float hv = bf2f((bf16raw)(unsigned short)v[e]);
#pragma unroll
            for (int l = 0; l < 5; l++) p[l] += hv * sWout[l * 128 + half * 64 + s * 8 + e];
        }
    }
#pragma unroll
    for (int l = 0; l < 5; l++) p[l] += __shfl_down(p[l], 1);

    float lossNode = 0.f;
    if (half == 0 && valid) {
        float lg[5], mx = -1e30f;
#pragma unroll
        for (int l = 0; l < 5; l++) {
            lg[l] = p[l] + bout[l];
            mx = fmaxf(mx, lg[l]);
        }
        float se = 0.f;
#pragma unroll
        for (int l = 0; l < 5; l++) se += __expf(lg[l] - mx);
        float lse = __logf(se) + mx;
        lossNode = lse - lg[labels[gg]];
        if (gg >= LEAF_OFF) {   // level-16 node: add leaf children terms
            const float* lv1 = lossv6 + (long)words[2 * gg + 1] * 6;
            const float* lv2 = lossv6 + (long)words[2 * gg + 2] * 6;
            lossNode += (lv1[5] - lv1[labels[2 * gg + 1]])
                      + (lv2[5] - lv2[labels[2 * gg + 2]]);
        }
        if (gg == 0) {
#pragma unroll
            for (int l = 0; l < 5; l++) out[l] = lg[l] - lse;
        }
    }
    if (half == 0) red[row] = lossNode;
    __syncthreads();
    if (t < 64) {
        float s = red[t] + red[t + 64];
#pragma unroll
        for (int d = 32; d > 0; d >>= 1) s += __shfl_down(s, d);
        if (t == 0) atomicAdd(&partials[blockIdx.x & 1023], s);
    }
}

__global__ __launch_bounds__(256) void k3_reduce(const float* __restrict__ partials,
                                                 float* __restrict__ out)
{
    const int t = threadIdx.x;
    float s = 0.f;
    for (int i = t; i < 1024; i += 256) s += partials[i];
#pragma unroll
    for (int d = 32; d > 0; d >>= 1) s += __shfl_down(s, d);
    __shared__ float red[4];
    if ((t & 63) == 0) red[t >> 6] = s;
    __syncthreads();
    if (t == 0) out[5] = red[0] + red[1] + red[2] + red[3];
}

// ---------------------------------------------------------------------------
extern "C" void kernel_launch(void* const* d_in, const int* in_sizes, int n_in,
                              void* d_out, int out_size, void* d_ws, size_t ws_size,
                              hipStream_t stream)
{
    const float* embeds = (const float*)d_in[0];
    const int* words = (const int*)d_in[1];
    const int* labels = (const int*)d_in[2];
    const float* Wix = (const float*)d_in[5],  *bix  = (const float*)d_in[6];
    const float* Wih = (const float*)d_in[7],  *bih  = (const float*)d_in[8];
    const float* Wfx = (const float*)d_in[9],  *bfx  = (const float*)d_in[10];
    const float* Wfh = (const float*)d_in[11], *bfh  = (const float*)d_in[12];
    const float* Wox = (const float*)d_in[13], *box_ = (const float*)d_in[14];
    const float* Woh = (const float*)d_in[15], *boh  = (const float*)d_in[16];
    const float* Wux = (const float*)d_in[17], *bux  = (const float*)d_in[18];
    const float* Wuh = (const float*)d_in[19], *buh  = (const float*)d_in[20];
    const float* Wout = (const float*)d_in[21], *bout = (const float*)d_in[22];
    float* out = (float*)d_out;

    char* ws = (char*)d_ws;
    const size_t treeElems = (size_t)NINT * 128;
    bf16raw* h_all = (bf16raw*)ws;
    bf16raw* c_all = h_all + treeElems;
    bf16raw* embeds_bf = c_all + treeElems;
    bf16raw* Bfrag = embeds_bf + (size_t)NVOCAB * 128;
    bf16raw* hc_leaf = Bfrag + 4 * 8 * KTS * 512;        // 288KB padded dedup B
    float* lossv6 = (float*)(hc_leaf + (size_t)NVOCAB * 256);
    float* bias_cat = lossv6 + (size_t)NVOCAB * 6;
    float* partials = bias_cat + 512;

    k_prep_embeds<<<(NVOCAB * 128 / 4 + 255) / 256, 256, 0, stream>>>(
        embeds, embeds_bf, NVOCAB * 128 / 4);
    k_prep_bcat<<<512, 128, 0, stream>>>(Wix, bix, Wih, bih, Wfx, bfx, Wfh, bfh,
                                         Wox, box_, Woh, boh, Wux, bux, Wuh, buh,
                                         Bfrag, bias_cat);
    hipMemsetAsync(partials, 0, 1024 * sizeof(float), stream);

    k_leafpre<<<(NVOCAB + 63) / 64, 256, 0, stream>>>(
        embeds_bf, Bfrag, bias_cat, Wout, bout, hc_leaf, lossv6, NVOCAB);

    for (int l = DEPTH - 2; l >= 0; --l) {
        const int n = 1 << l;
        k_level32<<<dim3((n + 31) / 32), 256, 0, stream>>>(
            embeds_bf, words, h_all, c_all, hc_leaf, Bfrag, bias_cat,
            n - 1, n, (l == DEPTH - 2) ? 1 : 0);
    }

    k_loss<<<(NINT + 127) / 128, 256, 0, stream>>>(
        h_all, words, labels, lossv6, Wout, bout, partials, out);
    k3_reduce<<<1, 256, 0, stream>>>(partials, out);
}